// Round 15
// baseline (1507.874 us; speedup 1.0000x reference)
//
#include <hip/hip_runtime.h>
#include <hip/hip_bf16.h>

// ---- problem constants ----
#define GF    7
#define TAPS  25
#define NCHNK 7          // K chunks; f-major: chunk ck <-> f = ck
#define NTILE 10         // tiles of 6 output rows
#define TROWS 6
#define SROWS 10         // 6 + 4 halo
#define NPOS  360        // 6*60 positions per tile
#define NF_   23         // ceil(360/16); frag 22 has 8 valid lanes

typedef __attribute__((ext_vector_type(8)))  __bf16 bf16x8;
typedef __attribute__((ext_vector_type(8)))  unsigned short u16x8;
typedef __attribute__((ext_vector_type(4)))  float f32x4;

__device__ __forceinline__ f32x4 mfma16(u16x8 a, u16x8 b, f32x4 c) {
  return __builtin_amdgcn_mfma_f32_16x16x32_bf16(
      __builtin_bit_cast(bf16x8, a), __builtin_bit_cast(bf16x8, b), c, 0, 0, 0);
}

// async global->LDS, 16B/lane; dest = wave-uniform base, HW adds lane*16
__device__ __forceinline__ void glds16(const unsigned short* g, unsigned short* l) {
  __builtin_amdgcn_global_load_lds(
      (__attribute__((address_space(1))) void*)g,
      (__attribute__((address_space(3))) void*)l, 16, 0, 0);
}

// w[o][c][f][kh][kw] f32 -> wt[ck][tap][o][c] bf16, LINEAR (A goes to REGISTERS,
// no LDS banks involved; per-tap block 4KB, coalesced 1KB per m-frag wave-load).
__global__ void wt_kernel(const float* __restrict__ w, unsigned short* __restrict__ wt) {
  int i = blockIdx.x * 256 + threadIdx.x;
  if (i >= NCHNK * TAPS * 64 * 32) return;
  int c   = i & 31;
  int o   = (i >> 5) & 63;
  int tap = (i >> 11) % TAPS;
  int ck  = i / (TAPS * 64 * 32);
  float v = w[((size_t)(o * 32 + c) * GF + ck) * TAPS + tap];
  __bf16 hb = (__bf16)v;
  wt[i] = __builtin_bit_cast(unsigned short, hb);
}

// x[b][c][gin][4096] f32 -> xt[b*33+gin][pos][32ch] bf16, swizzle BAKED:
// octet oct stored at slot oct ^ ((pos>>1)&3)  (B-read 2-way max).
__global__ void xt_kernel(const float* __restrict__ x, unsigned short* __restrict__ xt) {
  int blk = blockIdx.x;            // 264 planes * 64 rows
  int row = blk & 63;
  int pl  = blk >> 6;              // b*33 + gin
  int tid = threadIdx.x;
  int col = tid >> 2, oct = tid & 3;
  int b = pl / 33, gin = pl - 33 * b;
  const float* xp = x + (((size_t)b * 32 * 33 + gin) << 12) + row * 64 + col;
  u16x8 pk;
#pragma unroll
  for (int e = 0; e < 8; ++e) {
    float v = xp[(size_t)(8 * oct + e) * 135168];   // c-plane stride 33*4096
    pk[e] = __builtin_bit_cast(unsigned short, (__bf16)v);
  }
  int pos = row * 64 + col;
  *reinterpret_cast<u16x8*>(
      &xt[((size_t)pl << 17) + pos * 32 + 8 * (oct ^ ((pos >> 1) & 3))]) = pk;
}

// Block = (b, g, 6-row tile). 4 waves; wave = 4m(16 o) x <=6n(16 pos), 16x16x32.
// B from LDS Xs (40KB static, baked swizzle). A from GLOBAL->REGISTER with a
// 3-deep rotating buffer (a0/a1/a2, compile-time names via 25 macro-expanded
// phases) and distance-2 prefetch. Every phase ends in a volatile counted
// s_waitcnt vmcnt(8/4/0): loads are memory ops and CANNOT sink across two
// phase fences (fixes r14's compiler-sinking collapse). No Ws: LDS reads/phase
// 10 -> 6, barriers/block 72 -> 14. Within a ck no glds16 is outstanding, so
// the vmcnt ledger counts only A-loads (counting valid).
__global__ void __launch_bounds__(256, 2)
conv_kernel(const unsigned short* __restrict__ xt, const unsigned short* __restrict__ wt,
            const float* __restrict__ bias, const int* __restrict__ idx,
            float* __restrict__ out) {
  __shared__ __align__(16) unsigned short Xs[640 * 32];  // 40960 B

  // XCD-aware bijective swizzle: 1200 = 8 * 150
  const int bid0 = blockIdx.x;
  const int bid  = (bid0 & 7) * 150 + (bid0 >> 3);
  const int tile = bid % NTILE;
  const int g    = (bid / NTILE) % 15;
  const int b    = bid / (NTILE * 15);

  const int tid  = threadIdx.x;
  const int lane = tid & 63;
  const int wv   = tid >> 6;
  const int lo   = lane & 15;
  const int lk   = lane >> 4;
  const int r0   = tile * TROWS;

  int g7[NCHNK];
#pragma unroll
  for (int f = 0; f < NCHNK; ++f) g7[f] = idx[g * GF + f];
  asm volatile("s_waitcnt vmcnt(0) lgkmcnt(0)" ::: "memory");

  auto issue_xs = [&](int ckp) {  // 10 glds16/wave -> Xs (linear 40KB)
    const unsigned short* src =
        xt + (((size_t)(b * 33 + g7[ckp])) << 17) + r0 * 2048 + wv * 5120 + lane * 8;
#pragma unroll
    for (int t = 0; t < 10; ++t)
      glds16(src + t * 512, Xs + wv * 5120 + t * 512);
  };

  // A-frag: o = m*16+lo, ch = lk*8..lk*8+7; tap block = 2048 u16, m adds 512.
  const int alane = lo * 32 + lk * 8;
  auto load_a = [&](u16x8(&dst)[4], int ck, int tap) {
    const unsigned short* p = wt + ((ck * TAPS + tap) << 11) + alane;
#pragma unroll
    for (int m = 0; m < 4; ++m)
      dst[m] = *reinterpret_cast<const u16x8*>(p + m * 512);
  };

  // n-frags: wave owns {wv, wv+4, ...} -> (6,6,6,5). pb5[i][kw] as r12
  // (baked-swizzle B offset at kh=0; kh adds a *2048 ds_read immediate).
  int pb5[6][5];
  int pvalid = 0;
#pragma unroll
  for (int i = 0; i < 6; ++i) {
    int nf = wv + 4 * i;
#pragma unroll
    for (int kw = 0; kw < 5; ++kw) pb5[i][kw] = 8 * lk;
    if (nf < NF_) {
      int p  = nf * 16 + lo;
      int pc = (p < NPOS) ? p : 0;
      int ph = pc / 60;
      int pos0 = ph * 64 + (pc - 60 * ph);
#pragma unroll
      for (int kw = 0; kw < 5; ++kw) {
        int ptk = pos0 + kw;
        pb5[i][kw] = ptk * 32 + 8 * (lk ^ ((ptk >> 1) & 3));
      }
      pvalid = i + 1;
    }
  }

  f32x4 acc[4][6];
#pragma unroll
  for (int m = 0; m < 4; ++m)
#pragma unroll
    for (int i = 0; i < 6; ++i) acc[m][i] = f32x4{0.f, 0.f, 0.f, 0.f};

  u16x8 a0[4], a1[4], a2[4];

  issue_xs(0);
  load_a(a0, 0, 0);
  load_a(a1, 0, 1);
  asm volatile("s_waitcnt vmcnt(0) lgkmcnt(0)" ::: "memory");
  __builtin_amdgcn_s_barrier();

// One tap-phase. CUR = A-buffer for tap J (J%3), NXT = buffer for J+2.
// Loads for J+2 issue first; B-reads issue before the fence; the counted
// vmcnt fence guarantees A(J) landed and pins load-issue order.
#define PHASE(J, CUR, NXT)                                                  \
  {                                                                         \
    if ((J) <= 22) load_a(NXT, ck, (J) + 2);                                \
    u16x8 bf[6];                                                            \
    _Pragma("unroll")                                                       \
    for (int i = 0; i < 6; ++i)                                             \
      if (i < pvalid)                                                       \
        bf[i] = *reinterpret_cast<const u16x8*>(                            \
            &Xs[pb5[i][(J) % 5] + ((J) / 5) * 2048]);                       \
    if ((J) <= 22)                                                          \
      asm volatile("s_waitcnt vmcnt(8)" ::: "memory");                      \
    else if ((J) == 23)                                                     \
      asm volatile("s_waitcnt vmcnt(4)" ::: "memory");                      \
    else                                                                    \
      asm volatile("s_waitcnt vmcnt(0)" ::: "memory");                      \
    _Pragma("unroll")                                                       \
    for (int i = 0; i < 6; ++i)                                             \
      if (i < pvalid) {                                                     \
        _Pragma("unroll")                                                   \
        for (int m = 0; m < 4; ++m)                                         \
          acc[m][i] = mfma16(CUR[m], bf[i], acc[m][i]);                     \
      }                                                                     \
  }

#pragma unroll 1
  for (int ck = 0; ck < NCHNK; ++ck) {
    PHASE(0,  a0, a2) PHASE(1,  a1, a0) PHASE(2,  a2, a1)
    PHASE(3,  a0, a2) PHASE(4,  a1, a0) PHASE(5,  a2, a1)
    PHASE(6,  a0, a2) PHASE(7,  a1, a0) PHASE(8,  a2, a1)
    PHASE(9,  a0, a2) PHASE(10, a1, a0) PHASE(11, a2, a1)
    PHASE(12, a0, a2) PHASE(13, a1, a0) PHASE(14, a2, a1)
    PHASE(15, a0, a2) PHASE(16, a1, a0) PHASE(17, a2, a1)
    PHASE(18, a0, a2) PHASE(19, a1, a0) PHASE(20, a2, a1)
    PHASE(21, a0, a2) PHASE(22, a1, a0) PHASE(23, a2, a1)
    PHASE(24, a0, a2)

    if (ck + 1 < NCHNK) {
      __builtin_amdgcn_s_barrier();          // all waves done reading Xs(ck)
      issue_xs(ck + 1);                      // 10 glds16
      load_a(a0, ck + 1, 0);                 // re-prime A pipeline
      load_a(a1, ck + 1, 1);
      asm volatile("s_waitcnt vmcnt(0)" ::: "memory");  // Xs + A(0),A(1) landed
      __builtin_amdgcn_s_barrier();          // Xs visible to all waves
    }
  }
#undef PHASE

  // bias into registers: o = m*16 + 4*lk + v
  float bv[4][4];
#pragma unroll
  for (int m = 0; m < 4; ++m)
#pragma unroll
    for (int v = 0; v < 4; ++v) bv[m][v] = bias[m * 16 + 4 * lk + v];

  // epilogue: out[((b*64+o)*15+g)*3600 + tile*360 + p]
#pragma unroll
  for (int i = 0; i < 6; ++i) {
    if (i < pvalid) {
      int nf = wv + 4 * i;
      int p  = nf * 16 + lo;
      if (p < NPOS) {
        const size_t pb = (size_t)tile * NPOS + p;
#pragma unroll
        for (int m = 0; m < 4; ++m)
#pragma unroll
          for (int v = 0; v < 4; ++v) {
            int o = m * 16 + 4 * lk + v;
            out[((size_t)(b * 64 + o) * 15 + g) * 3600 + pb] = acc[m][i][v] + bv[m][v];
          }
      }
    }
  }
}

extern "C" void kernel_launch(void* const* d_in, const int* in_sizes, int n_in,
                              void* d_out, int out_size, void* d_ws, size_t ws_size,
                              hipStream_t stream) {
  const float* x      = (const float*)d_in[0];
  const float* weight = (const float*)d_in[1];
  const float* bias   = (const float*)d_in[2];
  const int*   idx    = (const int*)d_in[3];
  float* out = (float*)d_out;
  unsigned short* wt = (unsigned short*)d_ws;            // 716800 B
  unsigned short* xt = (unsigned short*)d_ws + 358400;   // 264*131072 u16 = 69.2 MB

  wt_kernel<<<(NCHNK * TAPS * 64 * 32 + 255) / 256, 256, 0, stream>>>(weight, wt);
  xt_kernel<<<264 * 64, 256, 0, stream>>>(x, xt);
  conv_kernel<<<8 * 15 * NTILE, 256, 0, stream>>>(xt, wt, bias, idx, out);
}

// Round 17
// 302.809 us; speedup vs baseline: 4.9796x; 4.9796x over previous
//
#include <hip/hip_runtime.h>
#include <hip/hip_bf16.h>

// ---- problem constants ----
#define GF    7
#define TAPS  25
#define NCHNK 7          // K chunks; f-major: chunk ck <-> f = ck
#define NTILE 10         // tiles of 6 output rows
#define TROWS 6
#define SROWS 10         // 6 + 4 halo
#define NPOS  360        // 6*60 positions per tile
#define NF_   23         // ceil(360/16); frag 22 has 8 valid lanes

typedef __attribute__((ext_vector_type(8)))  __bf16 bf16x8;
typedef __attribute__((ext_vector_type(8)))  unsigned short u16x8;
typedef __attribute__((ext_vector_type(4)))  float f32x4;

__device__ __forceinline__ f32x4 mfma16(u16x8 a, u16x8 b, f32x4 c) {
  return __builtin_amdgcn_mfma_f32_16x16x32_bf16(
      __builtin_bit_cast(bf16x8, a), __builtin_bit_cast(bf16x8, b), c, 0, 0, 0);
}

// async global->LDS, 16B/lane; dest = wave-uniform base, HW adds lane*16
__device__ __forceinline__ void glds16(const unsigned short* g, unsigned short* l) {
  __builtin_amdgcn_global_load_lds(
      (__attribute__((address_space(1))) void*)g,
      (__attribute__((address_space(3))) void*)l, 16, 0, 0);
}

// w[o][c][f][kh][kw] f32 -> wt[ck][tap][o][c] bf16, LINEAR. A-frags load
// global->REGISTER (1KB coalesced per m-frag); working set 4KB/tap, L1/L2-hot
// (all 8 waves/CU read the same block). Phase walk = +2048B linear.
__global__ void wt_kernel(const float* __restrict__ w, unsigned short* __restrict__ wt) {
  int i = blockIdx.x * 256 + threadIdx.x;
  if (i >= NCHNK * TAPS * 64 * 32) return;
  int c   = i & 31;
  int o   = (i >> 5) & 63;
  int tap = (i >> 11) % TAPS;
  int ck  = i / (TAPS * 64 * 32);
  float v = w[((size_t)(o * 32 + c) * GF + ck) * TAPS + tap];
  __bf16 hb = (__bf16)v;
  wt[i] = __builtin_bit_cast(unsigned short, hb);
}

// x[b][c][gin][4096] f32 -> xt[b*33+gin][pos][32ch] bf16, swizzle BAKED:
// octet oct stored at slot oct ^ ((pos>>1)&3)  (B-read 2-way max).
__global__ void xt_kernel(const float* __restrict__ x, unsigned short* __restrict__ xt) {
  int blk = blockIdx.x;            // 264 planes * 64 rows
  int row = blk & 63;
  int pl  = blk >> 6;              // b*33 + gin
  int tid = threadIdx.x;
  int col = tid >> 2, oct = tid & 3;
  int b = pl / 33, gin = pl - 33 * b;
  const float* xp = x + (((size_t)b * 32 * 33 + gin) << 12) + row * 64 + col;
  u16x8 pk;
#pragma unroll
  for (int e = 0; e < 8; ++e) {
    float v = xp[(size_t)(8 * oct + e) * 135168];   // c-plane stride 33*4096
    pk[e] = __builtin_bit_cast(unsigned short, (__bf16)v);
  }
  int pos = row * 64 + col;
  *reinterpret_cast<u16x8*>(
      &xt[((size_t)pl << 17) + pos * 32 + 8 * (oct ^ ((pos >> 1) & 3))]) = pk;
}

// Block = (b, g, 6-row tile). 4 waves; wave = 4m(16 o) x <=6n(16 pos), 16x16x32.
// B from LDS Xs (40KB static, baked swizzle, DMA-staged). A from GLOBAL via
// parity-static register double-buffer (aE/aO by compile-time tap&1; loads
// issue before the MFMAs; NO fences, NO launch-bounds squeeze -- r14 failed on
// the 170-VGPR cap, r15 on memory-clobber scratch; this runs at (256,2)=256).
// No Ws: LDS reads/phase 10->6 (576cy/CU < MFMA 932cy/SIMD -- tie broken);
// barriers/block 72->14. Inner loop stays zero-address-VALU.
__global__ void __launch_bounds__(256, 2)
conv_kernel(const unsigned short* __restrict__ xt, const unsigned short* __restrict__ wt,
            const float* __restrict__ bias, const int* __restrict__ idx,
            float* __restrict__ out) {
  __shared__ __align__(16) unsigned short Xs[640 * 32];  // 40960 B

  // XCD-aware bijective swizzle: 1200 = 8 * 150
  const int bid0 = blockIdx.x;
  const int bid  = (bid0 & 7) * 150 + (bid0 >> 3);
  const int tile = bid % NTILE;
  const int g    = (bid / NTILE) % 15;
  const int b    = bid / (NTILE * 15);

  const int tid  = threadIdx.x;
  const int lane = tid & 63;
  const int wv   = tid >> 6;
  const int lo   = lane & 15;
  const int lk   = lane >> 4;
  const int r0   = tile * TROWS;

  int g7[NCHNK];
#pragma unroll
  for (int f = 0; f < NCHNK; ++f) g7[f] = idx[g * GF + f];

  auto issue_xs = [&](int ckp) {  // 10 glds16/wave -> Xs (linear 40KB)
    const unsigned short* src =
        xt + (((size_t)(b * 33 + g7[ckp])) << 17) + r0 * 2048 + wv * 5120 + lane * 8;
#pragma unroll
    for (int t = 0; t < 10; ++t)
      glds16(src + t * 512, Xs + wv * 5120 + t * 512);
  };

  // A-frag: o = m*16+lo, ch = lk*8..; tap block 2048 u16, m adds 512.
  const int alane = lo * 32 + lk * 8;
  auto load_a = [&](u16x8* dst, int ck, int tap) {
    const unsigned short* p = wt + ((ck * TAPS + tap) << 11) + alane;
#pragma unroll
    for (int m = 0; m < 4; ++m)
      dst[m] = *reinterpret_cast<const u16x8*>(p + m * 512);
  };

  // n-frags: wave owns {wv, wv+4, ...} -> (6,6,6,5). pb5[i][kw]: baked-swizzle
  // B offset at (kh=0,kw); kh adds a *2048 ds_read immediate (kh-invariant swz).
  int pb5[6][5];
  int pvalid = 0;
#pragma unroll
  for (int i = 0; i < 6; ++i) {
    int nf = wv + 4 * i;
#pragma unroll
    for (int kw = 0; kw < 5; ++kw) pb5[i][kw] = 8 * lk;
    if (nf < NF_) {
      int p  = nf * 16 + lo;
      int pc = (p < NPOS) ? p : 0;
      int ph = pc / 60;
      int pos0 = ph * 64 + (pc - 60 * ph);
#pragma unroll
      for (int kw = 0; kw < 5; ++kw) {
        int ptk = pos0 + kw;
        pb5[i][kw] = ptk * 32 + 8 * (lk ^ ((ptk >> 1) & 3));
      }
      pvalid = i + 1;
    }
  }

  f32x4 acc[4][6];
#pragma unroll
  for (int m = 0; m < 4; ++m)
#pragma unroll
    for (int i = 0; i < 6; ++i) acc[m][i] = f32x4{0.f, 0.f, 0.f, 0.f};

  u16x8 aE[4], aO[4];
  load_a(aE, 0, 0);
  issue_xs(0);
  asm volatile("s_waitcnt vmcnt(0) lgkmcnt(0)" ::: "memory");
  __builtin_amdgcn_s_barrier();

#pragma unroll 1
  for (int ck = 0; ck < NCHNK; ++ck) {
#pragma unroll
    for (int kh = 0; kh < 5; ++kh) {
#pragma unroll
      for (int kw = 0; kw < 5; ++kw) {
        const int tap = kh * 5 + kw;              // compile-time
        u16x8* aCur = (tap & 1) ? aO : aE;        // static selection
        u16x8* aNxt = (tap & 1) ? aE : aO;
        if (tap < 24) load_a(aNxt, ck, tap + 1);  // overlaps MFMAs below
        u16x8 bf[6];
#pragma unroll
        for (int i = 0; i < 6; ++i)
          if (i < pvalid)
            bf[i] = *reinterpret_cast<const u16x8*>(&Xs[pb5[i][kw] + kh * 2048]);
#pragma unroll
        for (int i = 0; i < 6; ++i)
          if (i < pvalid)
#pragma unroll
            for (int m = 0; m < 4; ++m)
              acc[m][i] = mfma16(aCur[m], bf[i], acc[m][i]);
        if (tap == 24 && ck + 1 < NCHNK)
          load_a(aE, ck + 1, 0);                  // prime next ck (parity static)
      }
    }
    if (ck + 1 < NCHNK) {
      __builtin_amdgcn_s_barrier();               // all waves done reading Xs(ck)
      issue_xs(ck + 1);                           // 10 glds16
      asm volatile("s_waitcnt vmcnt(0)" ::: "memory");  // DMA (+A prime) landed
      __builtin_amdgcn_s_barrier();               // Xs visible to all waves
    }
  }

  // bias into registers: o = m*16 + 4*lk + v
  float bv[4][4];
#pragma unroll
  for (int m = 0; m < 4; ++m)
#pragma unroll
    for (int v = 0; v < 4; ++v) bv[m][v] = bias[m * 16 + 4 * lk + v];

  // epilogue: out[((b*64+o)*15+g)*3600 + tile*360 + p]
#pragma unroll
  for (int i = 0; i < 6; ++i) {
    if (i < pvalid) {
      int nf = wv + 4 * i;
      int p  = nf * 16 + lo;
      if (p < NPOS) {
        const size_t pb = (size_t)tile * NPOS + p;
#pragma unroll
        for (int m = 0; m < 4; ++m)
#pragma unroll
          for (int v = 0; v < 4; ++v) {
            int o = m * 16 + 4 * lk + v;
            out[((size_t)(b * 64 + o) * 15 + g) * 3600 + pb] = acc[m][i][v] + bv[m][v];
          }
      }
    }
  }
}

extern "C" void kernel_launch(void* const* d_in, const int* in_sizes, int n_in,
                              void* d_out, int out_size, void* d_ws, size_t ws_size,
                              hipStream_t stream) {
  const float* x      = (const float*)d_in[0];
  const float* weight = (const float*)d_in[1];
  const float* bias   = (const float*)d_in[2];
  const int*   idx    = (const int*)d_in[3];
  float* out = (float*)d_out;
  unsigned short* wt = (unsigned short*)d_ws;            // 716800 B
  unsigned short* xt = (unsigned short*)d_ws + 358400;   // 264*131072 u16 = 69.2 MB

  wt_kernel<<<(NCHNK * TAPS * 64 * 32 + 255) / 256, 256, 0, stream>>>(weight, wt);
  xt_kernel<<<264 * 64, 256, 0, stream>>>(x, xt);
  conv_kernel<<<8 * 15 * NTILE, 256, 0, stream>>>(xt, wt, bias, idx, out);
}